// Round 20
// baseline (378.349 us; speedup 1.0000x reference)
//
#include <hip/hip_runtime.h>
#include <hip/hip_fp16.h>
#include <cstdint>
#include <cstddef>

#define DIM 128
#define NG 128
#define NCLS 10
#define PSLICE 8
#define CPAD 64        // padded CSR row stride
#define NOWN 256       // fine owners; one k_place block per owner
#define RPB 391        // rows per owner
#define NPBLK 1024     // k_part partition-blocks
#define WTBLK 192      // extra blocks in k_part doing the weight transpose
#define OCAP 16        // per (owner,block) sub-bucket capacity
#define OVCAP 65536    // global overflow capacity

typedef _Float16 f16;
typedef __attribute__((ext_vector_type(8))) _Float16 f16x8;
typedef __attribute__((ext_vector_type(4))) float f32x4;
typedef __attribute__((ext_vector_type(4))) unsigned u32x4;

// ---------------- preprocessing ----------------

// Blocks [0,NPBLK): partition edges into 256 owner buckets (4B entries,
// LDS counters only). Blocks [NPBLK, NPBLK+WTBLK): W fp32->fp16 transpose.
__global__ __launch_bounds__(256) void k_part(
    const int* __restrict__ rw, const int* __restrict__ cl, int E,
    unsigned* __restrict__ buckets, int* __restrict__ bcnt,
    unsigned long long* __restrict__ ovf, int* __restrict__ ovfn,
    const float* __restrict__ W1, const float* __restrict__ W2,
    const float* __restrict__ W3, __half* __restrict__ Wt1,
    __half* __restrict__ Wt2, __half* __restrict__ Wt3) {
  if (blockIdx.x >= NPBLK) {
    int gi = (blockIdx.x - NPBLK) * 256 + threadIdx.x;
    int m = gi / (DIM * DIM);
    int i = gi % (DIM * DIM);
    const float* W = (m == 0) ? W1 : (m == 1) ? W2 : W3;
    __half* Wt = (m == 0) ? Wt1 : (m == 1) ? Wt2 : Wt3;
    int k = i >> 7, c = i & 127;
    Wt[(size_t)c * DIM + k] = __float2half(W[(size_t)k * DIM + c]);
    return;
  }
  __shared__ int lcnt[NOWN];
  if (threadIdx.x < NOWN) lcnt[threadIdx.x] = 0;
  __syncthreads();
  int b = blockIdx.x;
  int C = (((E + NPBLK - 1) / NPBLK + 3) & ~3);
  int s = b * C;
  int e = s + C;
  if (e > E) e = E;
  auto put = [&](int r, int c) {
    int o = (unsigned)r / RPB;
    int li = r - o * RPB;
    int sl = atomicAdd(&lcnt[o], 1);
    if (sl < OCAP) {
      buckets[((size_t)o * NPBLK + b) * OCAP + sl] =
          ((unsigned)li << 17) | (unsigned)c;
    } else {
      int oi = atomicAdd(ovfn, 1);
      if (oi < OVCAP)
        ovf[oi] = ((unsigned long long)(unsigned)r << 32) | (unsigned)c;
    }
  };
  for (int i = s + (int)threadIdx.x * 4; i < e; i += 1024) {
    if (i + 3 < e) {
      int4 r4 = *(const int4*)(rw + i);
      int4 c4 = *(const int4*)(cl + i);
      put(r4.x, c4.x);
      put(r4.y, c4.y);
      put(r4.z, c4.z);
      put(r4.w, c4.w);
    } else {
      for (int j = i; j < e; ++j) put(rw[j], cl[j]);
    }
  }
  __syncthreads();
  if (threadIdx.x < NOWN) {
    int v = lcnt[threadIdx.x];
    bcnt[threadIdx.x * NPBLK + b] = v < OCAP ? v : OCAP;
  }
}

__global__ __launch_bounds__(256) void k_place(
    const unsigned* __restrict__ buckets, const int* __restrict__ bcnt,
    const unsigned long long* __restrict__ ovf, const int* __restrict__ ovfn,
    int* __restrict__ cnt, float* __restrict__ dis, int* __restrict__ csrc,
    int N) {
  extern __shared__ int sm[];
  int* lcnt = sm;
  int* csr = sm + ((RPB + 3) & ~3);
  int o = blockIdx.x;
  int r0 = o * RPB;
  int rows = N - r0;
  if (rows > RPB) rows = RPB;
  if (rows <= 0) return;
  for (int i = threadIdx.x; i < rows; i += 256) lcnt[i] = 0;
  __syncthreads();
  const int* bc = bcnt + o * NPBLK;
  const unsigned* bp = buckets + (size_t)o * NPBLK * OCAP;
  for (int j = (int)threadIdx.x; j < NPBLK * OCAP; j += 256) {
    int seg = j >> 4;
    int pos = j & 15;
    if (pos < bc[seg]) {
      unsigned ent = bp[j];
      int li = (int)(ent >> 17);
      int c = (int)(ent & 0x1ffffu);
      int sl = atomicAdd(&lcnt[li], 1);
      if (sl < CPAD) csr[(li << 6) + sl] = c;
    }
  }
  int nov = *ovfn;
  if (nov > OVCAP) nov = OVCAP;
  for (int j = (int)threadIdx.x; j < nov; j += 256) {
    unsigned long long ent = ovf[j];
    int r = (int)(unsigned)(ent >> 32);
    int li = r - r0;
    if (li >= 0 && li < rows) {
      int c = (int)(unsigned)(ent & 0xffffffffu);
      int sl = atomicAdd(&lcnt[li], 1);
      if (sl < CPAD) csr[(li << 6) + sl] = c;
    }
  }
  __syncthreads();
  u32x4* dst = (u32x4*)(csrc + ((size_t)r0 << 6));
  const u32x4* src = (const u32x4*)csr;
  int n4 = rows * 16;
  for (int j = (int)threadIdx.x; j < n4; j += 256)
    __builtin_nontemporal_store(src[j], dst + j);
  for (int i = threadIdx.x; i < rows; i += 256) {
    int v = lcnt[i];
    cnt[r0 + i] = v;
    dis[r0 + i] = rsqrtf((float)(v + 1));
  }
}

// ---------------- GEMM (MFMA): H' = dis ⊙ (A @ W + b), fp16 out ----------------

template <int FP32IN>
__global__ __launch_bounds__(256, 3) void k_gemm(
    const void* __restrict__ Ain, const __half* __restrict__ Wt,
    const float* __restrict__ bias, const float* __restrict__ dis,
    __half* __restrict__ Hh, int N) {
  int t = threadIdx.x;
  int lane = t & 63;
  int wv = t >> 6;
  int l15 = lane & 15, lg = lane >> 4;
  int cb = (wv & 1) * 64;  // col base for this wave

  f16x8 bfr[4][4];  // [ks][ct]
#pragma unroll
  for (int ct = 0; ct < 4; ++ct) {
    int c = cb + ct * 16 + l15;
    const f16* wp = (const f16*)Wt + (size_t)c * DIM + lg * 8;
#pragma unroll
    for (int ks = 0; ks < 4; ++ks) bfr[ks][ct] = *(const f16x8*)(wp + ks * 32);
  }
  float bv[4];
#pragma unroll
  for (int ct = 0; ct < 4; ++ct) bv[ct] = bias[cb + ct * 16 + l15];

  const int nt2 = (N + 31) / 32;
  for (int t2 = blockIdx.x; t2 < nt2; t2 += gridDim.x) {
    int row0 = t2 * 32 + (wv >> 1) * 16;
    int rA = row0 + l15;
    if (rA > N - 1) rA = N - 1;
    f16x8 afr[4];
    if constexpr (FP32IN) {
      const float* ap = (const float*)Ain + (size_t)rA * DIM + lg * 8;
#pragma unroll
      for (int ks = 0; ks < 4; ++ks) {
        float4 v0 = *(const float4*)(ap + ks * 32);
        float4 v1 = *(const float4*)(ap + ks * 32 + 4);
        f16x8 a;
        a[0] = (f16)v0.x; a[1] = (f16)v0.y; a[2] = (f16)v0.z; a[3] = (f16)v0.w;
        a[4] = (f16)v1.x; a[5] = (f16)v1.y; a[6] = (f16)v1.z; a[7] = (f16)v1.w;
        afr[ks] = a;
      }
    } else {
      const f16* ap = (const f16*)Ain + (size_t)rA * DIM + lg * 8;
#pragma unroll
      for (int ks = 0; ks < 4; ++ks) afr[ks] = *(const f16x8*)(ap + ks * 32);
    }

    f32x4 acc[4];
#pragma unroll
    for (int ct = 0; ct < 4; ++ct) acc[ct] = (f32x4){0.f, 0.f, 0.f, 0.f};
#pragma unroll
    for (int ks = 0; ks < 4; ++ks)
#pragma unroll
      for (int ct = 0; ct < 4; ++ct)
        acc[ct] = __builtin_amdgcn_mfma_f32_16x16x32_f16(afr[ks], bfr[ks][ct], acc[ct], 0, 0, 0);

#pragma unroll
    for (int j = 0; j < 4; ++j) {
      int r = row0 + lg * 4 + j;
      if (r < N) {
        float dr = dis[r];
#pragma unroll
        for (int ct = 0; ct < 4; ++ct) {
          float o = (acc[ct][j] + bv[ct]) * dr;
          Hh[(size_t)r * DIM + cb + ct * 16 + l15] = __float2half(o);
        }
      }
    }
  }
}

// ---------------- aggregation (4 rows/wave, 16 lanes x 16B) ----------------
// STORE_NT=1 for the last layer (output read once by pooling; keep L2 clean).

template <int STORE_NT>
__global__ __launch_bounds__(256) void k_agg(
    const __half* __restrict__ Hh, __half* __restrict__ Ah,
    const int* __restrict__ csrc, const int* __restrict__ cntA,
    const float* __restrict__ dis, int N) {
  int wave = (int)(((size_t)blockIdx.x * blockDim.x + threadIdx.x) >> 6);
  int lane = threadIdx.x & 63;
  int g = lane >> 4;   // row group (0..3)
  int q = lane & 15;   // 16B slice owner
  int r = wave * 4 + g;
  if (r >= N) return;
  int cnt = cntA[r];
  if (cnt > CPAD) cnt = CPAD;
  float dr = dis[r];
  const int* cp = csrc + ((size_t)r << 6);
  const f16* hb = (const f16*)Hh + q * 8;

  float4 aA0 = {0,0,0,0}, aA1 = {0,0,0,0};
  float4 aB0 = {0,0,0,0}, aB1 = {0,0,0,0};
  float4 aC0 = {0,0,0,0}, aC1 = {0,0,0,0};
  float4 aD0 = {0,0,0,0}, aD1 = {0,0,0,0};

#define ACC8(u, x0, x1)                                                   \
  {                                                                       \
    float2 f_;                                                            \
    f_ = __half22float2(*reinterpret_cast<const __half2*>(&(u).x));       \
    x0.x += f_.x; x0.y += f_.y;                                           \
    f_ = __half22float2(*reinterpret_cast<const __half2*>(&(u).y));       \
    x0.z += f_.x; x0.w += f_.y;                                           \
    f_ = __half22float2(*reinterpret_cast<const __half2*>(&(u).z));       \
    x1.x += f_.x; x1.y += f_.y;                                           \
    f_ = __half22float2(*reinterpret_cast<const __half2*>(&(u).w));       \
    x1.z += f_.x; x1.w += f_.y;                                           \
  }

  int i = 0;
  for (; i + 3 < cnt; i += 4) {
    int c0 = cp[i], c1 = cp[i + 1], c2 = cp[i + 2], c3 = cp[i + 3];
    uint4 u0 = *(const uint4*)(hb + (size_t)c0 * DIM);
    uint4 u1 = *(const uint4*)(hb + (size_t)c1 * DIM);
    uint4 u2 = *(const uint4*)(hb + (size_t)c2 * DIM);
    uint4 u3 = *(const uint4*)(hb + (size_t)c3 * DIM);
    ACC8(u0, aA0, aA1);
    ACC8(u1, aB0, aB1);
    ACC8(u2, aC0, aC1);
    ACC8(u3, aD0, aD1);
  }
  for (; i < cnt; ++i) {
    int c0 = cp[i];
    uint4 u0 = *(const uint4*)(hb + (size_t)c0 * DIM);
    ACC8(u0, aA0, aA1);
  }
  // self term
  {
    uint4 us = *(const uint4*)(hb + (size_t)r * DIM);
    ACC8(us, aA0, aA1);
  }
#undef ACC8
  float4 s0, s1;
  s0.x = (aA0.x + aB0.x) + (aC0.x + aD0.x);
  s0.y = (aA0.y + aB0.y) + (aC0.y + aD0.y);
  s0.z = (aA0.z + aB0.z) + (aC0.z + aD0.z);
  s0.w = (aA0.w + aB0.w) + (aC0.w + aD0.w);
  s1.x = (aA1.x + aB1.x) + (aC1.x + aD1.x);
  s1.y = (aA1.y + aB1.y) + (aC1.y + aD1.y);
  s1.z = (aA1.z + aB1.z) + (aC1.z + aD1.z);
  s1.w = (aA1.w + aB1.w) + (aC1.w + aD1.w);
  float o0 = fmaxf(dr * s0.x, 0.f), o1 = fmaxf(dr * s0.y, 0.f);
  float o2 = fmaxf(dr * s0.z, 0.f), o3 = fmaxf(dr * s0.w, 0.f);
  float o4 = fmaxf(dr * s1.x, 0.f), o5 = fmaxf(dr * s1.y, 0.f);
  float o6 = fmaxf(dr * s1.z, 0.f), o7 = fmaxf(dr * s1.w, 0.f);
  __half2 p0 = __floats2half2_rn(o0, o1);
  __half2 p1 = __floats2half2_rn(o2, o3);
  __half2 p2 = __floats2half2_rn(o4, o5);
  __half2 p3 = __floats2half2_rn(o6, o7);
  u32x4 u;
  u.x = *(unsigned int*)&p0;
  u.y = *(unsigned int*)&p1;
  u.z = *(unsigned int*)&p2;
  u.w = *(unsigned int*)&p3;
  u32x4* dst = (u32x4*)((f16*)Ah + (size_t)r * DIM + q * 8);
  if constexpr (STORE_NT) {
    __builtin_nontemporal_store(u, dst);
  } else {
    *dst = u;
  }
}

// ---------------- pooling + head ----------------

__device__ __forceinline__ int lower_bound_batch(const int* batch, int N, int g) {
  int lo = 0, hi = N;
  while (lo < hi) {
    int mid = (lo + hi) >> 1;
    if (batch[mid] < g) lo = mid + 1; else hi = mid;
  }
  return lo;
}

__global__ void k_pool1(const __half* __restrict__ A, const int* __restrict__ batch,
                        int N, float* __restrict__ part) {
  int g = blockIdx.x / PSLICE, sl = blockIdx.x % PSLICE;
  int c = threadIdx.x;  // 128
  int s = lower_bound_batch(batch, N, g);
  int e = lower_bound_batch(batch, N, g + 1);
  int len = e - s;
  int ns = s + (len * sl) / PSLICE;
  int ne = s + (len * (sl + 1)) / PSLICE;
  float sum = 0.f, mx = -INFINITY;
  for (int n = ns; n < ne; ++n) {
    float v = __half2float(A[(size_t)n * DIM + c]);
    sum += v;
    mx = fmaxf(mx, v);
  }
  part[((size_t)(g * PSLICE + sl) * 2 + 0) * DIM + c] = sum;
  part[((size_t)(g * PSLICE + sl) * 2 + 1) * DIM + c] = mx;
}

__global__ void k_head(const float* __restrict__ part, const int* __restrict__ batch,
                       int N, const float* __restrict__ Wm1,
                       const float* __restrict__ bm1, const float* __restrict__ Wm2,
                       const float* __restrict__ bm2, float* __restrict__ out) {
  __shared__ float gs[256];
  __shared__ float hs[DIM];
  int g = blockIdx.x;
  int c = threadIdx.x;  // 128
  float sum = 0.f, mx = -INFINITY;
  for (int sl = 0; sl < PSLICE; ++sl) {
    sum += part[((size_t)(g * PSLICE + sl) * 2 + 0) * DIM + c];
    mx = fmaxf(mx, part[((size_t)(g * PSLICE + sl) * 2 + 1) * DIM + c]);
  }
  int s = lower_bound_batch(batch, N, g);
  int e = lower_bound_batch(batch, N, g + 1);
  gs[c] = sum / ((float)(e - s) + 1e-12f);
  gs[c + 128] = mx;
  __syncthreads();
  float acc = bm1[c];
#pragma unroll 8
  for (int k = 0; k < 256; ++k) acc = fmaf(gs[k], Wm1[k * DIM + c], acc);
  hs[c] = fmaxf(acc, 0.f);
  __syncthreads();
  if (c < NCLS) {
    float a2 = bm2[c];
#pragma unroll 8
    for (int k = 0; k < DIM; ++k) a2 = fmaf(hs[k], Wm2[k * NCLS + c], a2);
    out[(size_t)g * NCLS + c] = a2;
  }
}

// ---------------- host ----------------

static inline size_t al256(size_t x) { return (x + 255) & ~(size_t)255; }

extern "C" void kernel_launch(void* const* d_in, const int* in_sizes, int n_in,
                              void* d_out, int out_size, void* d_ws, size_t ws_size,
                              hipStream_t stream) {
  const float* X = (const float*)d_in[0];
  const int* EI = (const int*)d_in[1];
  const int* batch = (const int*)d_in[2];
  const float* W1 = (const float*)d_in[4];
  const float* b1 = (const float*)d_in[5];
  const float* W2 = (const float*)d_in[6];
  const float* b2 = (const float*)d_in[7];
  const float* W3 = (const float*)d_in[8];
  const float* b3 = (const float*)d_in[9];
  const float* Wm1 = (const float*)d_in[10];
  const float* bm1 = (const float*)d_in[11];
  const float* Wm2 = (const float*)d_in[12];
  const float* bm2 = (const float*)d_in[13];
  float* OUT = (float*)d_out;

  const int N = in_sizes[0] / DIM;
  const int E = in_sizes[1] / 2;
  const int G = NG;

  const int* EI_row = EI;
  const int* EI_col = EI + E;

  char* p = (char*)d_ws;
  size_t off = 0;
  auto take = [&](size_t bytes) { void* r = p + off; off = al256(off + bytes); return r; };

  int* cnt = (int*)take((size_t)N * 4);
  int* bcnt = (int*)take((size_t)NOWN * NPBLK * 4);
  int* ovfn = (int*)take(256);
  unsigned long long* ovf = (unsigned long long*)take((size_t)OVCAP * 8);
  float* dis = (float*)take((size_t)N * 4);
  int* csrc = (int*)take((size_t)N * CPAD * 4);
  unsigned* buckets = (unsigned*)take((size_t)NOWN * NPBLK * OCAP * 4);
  __half* Hh = (__half*)take((size_t)N * DIM * 2);
  __half* Ah = (__half*)take((size_t)N * DIM * 2);
  __half* Wt1 = (__half*)take((size_t)DIM * DIM * 2);
  __half* Wt2 = (__half*)take((size_t)DIM * DIM * 2);
  __half* Wt3 = (__half*)take((size_t)DIM * DIM * 2);
  float* part = (float*)take((size_t)G * PSLICE * 2 * DIM * 4);
  (void)ws_size; (void)n_in; (void)out_size;

  hipMemsetAsync(ovfn, 0, 4, stream);

  // preprocessing: partition (+ fused weight transpose), LDS-CSR assembly
  k_part<<<NPBLK + WTBLK, 256, 0, stream>>>(EI_row, EI_col, E, buckets, bcnt,
                                            ovf, ovfn, W1, W2, W3, Wt1, Wt2, Wt3);
  const int placeLds = ((RPB + 3) & ~3) * 4 + RPB * 64 * 4;  // ~100.5 KB
  k_place<<<NOWN, 256, placeLds, stream>>>(buckets, bcnt, ovf, ovfn, cnt, dis, csrc, N);

  const int aggBlocks = (N * 16 + 255) / 256;

  // layer 1 (fp32 X cast in-register inside gemm)
  k_gemm<1><<<512, 256, 0, stream>>>(X, Wt1, b1, dis, Hh, N);
  k_agg<0><<<aggBlocks, 256, 0, stream>>>(Hh, Ah, csrc, cnt, dis, N);
  // layer 2
  k_gemm<0><<<512, 256, 0, stream>>>(Ah, Wt2, b2, dis, Hh, N);
  k_agg<0><<<aggBlocks, 256, 0, stream>>>(Hh, Ah, csrc, cnt, dis, N);
  // layer 3
  k_gemm<0><<<512, 256, 0, stream>>>(Ah, Wt3, b3, dis, Hh, N);
  k_agg<1><<<aggBlocks, 256, 0, stream>>>(Hh, Ah, csrc, cnt, dis, N);

  // pooling + head
  k_pool1<<<G * PSLICE, DIM, 0, stream>>>(Ah, batch, N, part);
  k_head<<<G, DIM, 0, stream>>>(part, batch, N, Wm1, bm1, Wm2, bm2, OUT);
}

// Round 21
// 368.325 us; speedup vs baseline: 1.0272x; 1.0272x over previous
//
#include <hip/hip_runtime.h>
#include <hip/hip_fp16.h>
#include <cstdint>
#include <cstddef>

#define DIM 128
#define NG 128
#define NCLS 10
#define PSLICE 8
#define CPAD 64        // padded CSR row stride
#define NOWN 256       // fine owners; one k_place block per owner
#define RPB 391        // rows per owner
#define NPBLK 1024     // k_part partition-blocks
#define WTBLK 192      // extra blocks in k_part doing the weight transpose
#define OCAP 16        // per (owner,block) sub-bucket capacity
#define OVCAP 65536    // global overflow capacity

typedef _Float16 f16;
typedef __attribute__((ext_vector_type(8))) _Float16 f16x8;
typedef __attribute__((ext_vector_type(4))) float f32x4;
typedef __attribute__((ext_vector_type(4))) unsigned u32x4;

// ---------------- preprocessing ----------------

__global__ __launch_bounds__(256) void k_part(
    const int* __restrict__ rw, const int* __restrict__ cl, int E,
    unsigned* __restrict__ buckets, int* __restrict__ bcnt,
    unsigned long long* __restrict__ ovf, int* __restrict__ ovfn,
    const float* __restrict__ W1, const float* __restrict__ W2,
    const float* __restrict__ W3, __half* __restrict__ Wt1,
    __half* __restrict__ Wt2, __half* __restrict__ Wt3) {
  if (blockIdx.x >= NPBLK) {
    int gi = (blockIdx.x - NPBLK) * 256 + threadIdx.x;
    int m = gi / (DIM * DIM);
    int i = gi % (DIM * DIM);
    const float* W = (m == 0) ? W1 : (m == 1) ? W2 : W3;
    __half* Wt = (m == 0) ? Wt1 : (m == 1) ? Wt2 : Wt3;
    int k = i >> 7, c = i & 127;
    Wt[(size_t)c * DIM + k] = __float2half(W[(size_t)k * DIM + c]);
    return;
  }
  __shared__ int lcnt[NOWN];
  if (threadIdx.x < NOWN) lcnt[threadIdx.x] = 0;
  __syncthreads();
  int b = blockIdx.x;
  int C = (((E + NPBLK - 1) / NPBLK + 3) & ~3);
  int s = b * C;
  int e = s + C;
  if (e > E) e = E;
  auto put = [&](int r, int c) {
    int o = (unsigned)r / RPB;
    int li = r - o * RPB;
    int sl = atomicAdd(&lcnt[o], 1);
    if (sl < OCAP) {
      buckets[((size_t)o * NPBLK + b) * OCAP + sl] =
          ((unsigned)li << 17) | (unsigned)c;
    } else {
      int oi = atomicAdd(ovfn, 1);
      if (oi < OVCAP)
        ovf[oi] = ((unsigned long long)(unsigned)r << 32) | (unsigned)c;
    }
  };
  for (int i = s + (int)threadIdx.x * 4; i < e; i += 1024) {
    if (i + 3 < e) {
      int4 r4 = *(const int4*)(rw + i);
      int4 c4 = *(const int4*)(cl + i);
      put(r4.x, c4.x);
      put(r4.y, c4.y);
      put(r4.z, c4.z);
      put(r4.w, c4.w);
    } else {
      for (int j = i; j < e; ++j) put(rw[j], cl[j]);
    }
  }
  __syncthreads();
  if (threadIdx.x < NOWN) {
    int v = lcnt[threadIdx.x];
    bcnt[threadIdx.x * NPBLK + b] = v < OCAP ? v : OCAP;
  }
}

__global__ __launch_bounds__(256) void k_place(
    const unsigned* __restrict__ buckets, const int* __restrict__ bcnt,
    const unsigned long long* __restrict__ ovf, const int* __restrict__ ovfn,
    int* __restrict__ cnt, float* __restrict__ dis, int* __restrict__ csrc,
    int N) {
  extern __shared__ int sm[];
  int* lcnt = sm;
  int* csr = sm + ((RPB + 3) & ~3);
  int o = blockIdx.x;
  int r0 = o * RPB;
  int rows = N - r0;
  if (rows > RPB) rows = RPB;
  if (rows <= 0) return;
  for (int i = threadIdx.x; i < rows; i += 256) lcnt[i] = 0;
  __syncthreads();
  const int* bc = bcnt + o * NPBLK;
  const unsigned* bp = buckets + (size_t)o * NPBLK * OCAP;
  for (int j = (int)threadIdx.x; j < NPBLK * OCAP; j += 256) {
    int seg = j >> 4;
    int pos = j & 15;
    if (pos < bc[seg]) {
      unsigned ent = bp[j];
      int li = (int)(ent >> 17);
      int c = (int)(ent & 0x1ffffu);
      int sl = atomicAdd(&lcnt[li], 1);
      if (sl < CPAD) csr[(li << 6) + sl] = c;
    }
  }
  int nov = *ovfn;
  if (nov > OVCAP) nov = OVCAP;
  for (int j = (int)threadIdx.x; j < nov; j += 256) {
    unsigned long long ent = ovf[j];
    int r = (int)(unsigned)(ent >> 32);
    int li = r - r0;
    if (li >= 0 && li < rows) {
      int c = (int)(unsigned)(ent & 0xffffffffu);
      int sl = atomicAdd(&lcnt[li], 1);
      if (sl < CPAD) csr[(li << 6) + sl] = c;
    }
  }
  __syncthreads();
  u32x4* dst = (u32x4*)(csrc + ((size_t)r0 << 6));
  const u32x4* src = (const u32x4*)csr;
  int n4 = rows * 16;
  for (int j = (int)threadIdx.x; j < n4; j += 256) dst[j] = src[j];
  for (int i = threadIdx.x; i < rows; i += 256) {
    int v = lcnt[i];
    cnt[r0 + i] = v;
    dis[r0 + i] = rsqrtf((float)(v + 1));
  }
}

// ---------------- GEMM (MFMA): H' = dis ⊙ (A @ W + b), fp16 out ----------------

template <int FP32IN>
__global__ __launch_bounds__(256, 3) void k_gemm(
    const void* __restrict__ Ain, const __half* __restrict__ Wt,
    const float* __restrict__ bias, const float* __restrict__ dis,
    __half* __restrict__ Hh, int N) {
  int t = threadIdx.x;
  int lane = t & 63;
  int wv = t >> 6;
  int l15 = lane & 15, lg = lane >> 4;
  int cb = (wv & 1) * 64;

  f16x8 bfr[4][4];
#pragma unroll
  for (int ct = 0; ct < 4; ++ct) {
    int c = cb + ct * 16 + l15;
    const f16* wp = (const f16*)Wt + (size_t)c * DIM + lg * 8;
#pragma unroll
    for (int ks = 0; ks < 4; ++ks) bfr[ks][ct] = *(const f16x8*)(wp + ks * 32);
  }
  float bv[4];
#pragma unroll
  for (int ct = 0; ct < 4; ++ct) bv[ct] = bias[cb + ct * 16 + l15];

  const int nt2 = (N + 31) / 32;
  for (int t2 = blockIdx.x; t2 < nt2; t2 += gridDim.x) {
    int row0 = t2 * 32 + (wv >> 1) * 16;
    int rA = row0 + l15;
    if (rA > N - 1) rA = N - 1;
    f16x8 afr[4];
    if constexpr (FP32IN) {
      const float* ap = (const float*)Ain + (size_t)rA * DIM + lg * 8;
#pragma unroll
      for (int ks = 0; ks < 4; ++ks) {
        float4 v0 = *(const float4*)(ap + ks * 32);
        float4 v1 = *(const float4*)(ap + ks * 32 + 4);
        f16x8 a;
        a[0] = (f16)v0.x; a[1] = (f16)v0.y; a[2] = (f16)v0.z; a[3] = (f16)v0.w;
        a[4] = (f16)v1.x; a[5] = (f16)v1.y; a[6] = (f16)v1.z; a[7] = (f16)v1.w;
        afr[ks] = a;
      }
    } else {
      const f16* ap = (const f16*)Ain + (size_t)rA * DIM + lg * 8;
#pragma unroll
      for (int ks = 0; ks < 4; ++ks) afr[ks] = *(const f16x8*)(ap + ks * 32);
    }

    f32x4 acc[4];
#pragma unroll
    for (int ct = 0; ct < 4; ++ct) acc[ct] = (f32x4){0.f, 0.f, 0.f, 0.f};
#pragma unroll
    for (int ks = 0; ks < 4; ++ks)
#pragma unroll
      for (int ct = 0; ct < 4; ++ct)
        acc[ct] = __builtin_amdgcn_mfma_f32_16x16x32_f16(afr[ks], bfr[ks][ct], acc[ct], 0, 0, 0);

#pragma unroll
    for (int j = 0; j < 4; ++j) {
      int r = row0 + lg * 4 + j;
      if (r < N) {
        float dr = dis[r];
#pragma unroll
        for (int ct = 0; ct < 4; ++ct) {
          float o = (acc[ct][j] + bv[ct]) * dr;
          Hh[(size_t)r * DIM + cb + ct * 16 + l15] = __float2half(o);
        }
      }
    }
  }
}

// ---------------- agg accumulate helper ----------------
#define ACC8(u, x0, x1)                                                   \
  {                                                                       \
    float2 f_;                                                            \
    f_ = __half22float2(*reinterpret_cast<const __half2*>(&(u).x));       \
    x0.x += f_.x; x0.y += f_.y;                                           \
    f_ = __half22float2(*reinterpret_cast<const __half2*>(&(u).y));       \
    x0.z += f_.x; x0.w += f_.y;                                           \
    f_ = __half22float2(*reinterpret_cast<const __half2*>(&(u).z));       \
    x1.x += f_.x; x1.y += f_.y;                                           \
    f_ = __half22float2(*reinterpret_cast<const __half2*>(&(u).w));       \
    x1.z += f_.x; x1.w += f_.y;                                           \
  }

// ---------------- fused agg_i + gemm_{i+1} ----------------
// Block = 16 rows. Phase 1: agg (4 rows/wave, 16 lanes x 16B) -> LDS [16][136].
// Phase 2: MFMA 16-row tile, A-frags from LDS; wave covers 32 cols.

__global__ __launch_bounds__(256, 4) void k_agge(
    const __half* __restrict__ Hh, const __half* __restrict__ Wt,
    const float* __restrict__ bias, const float* __restrict__ dis,
    __half* __restrict__ Ho, const int* __restrict__ csrc,
    const int* __restrict__ cntA, int N) {
  __shared__ f16 smA[16][136];  // padded: 272B stride -> 2-way bank alias (free)
  int t = threadIdx.x;
  int lane = t & 63;
  int wv = t >> 6;
  // ---- phase 1: aggregate rows tile*16 + wv*4 + g
  {
    int g = lane >> 4;
    int q = lane & 15;
    int rowin = wv * 4 + g;
    int r = blockIdx.x * 16 + rowin;
    if (r < N) {
      int cnt = cntA[r];
      if (cnt > CPAD) cnt = CPAD;
      float dr = dis[r];
      const int* cp = csrc + ((size_t)r << 6);
      const f16* hb = (const f16*)Hh + q * 8;
      float4 aA0 = {0,0,0,0}, aA1 = {0,0,0,0};
      float4 aB0 = {0,0,0,0}, aB1 = {0,0,0,0};
      float4 aC0 = {0,0,0,0}, aC1 = {0,0,0,0};
      float4 aD0 = {0,0,0,0}, aD1 = {0,0,0,0};
      int i = 0;
      for (; i + 3 < cnt; i += 4) {
        int c0 = cp[i], c1 = cp[i + 1], c2 = cp[i + 2], c3 = cp[i + 3];
        uint4 u0 = *(const uint4*)(hb + (size_t)c0 * DIM);
        uint4 u1 = *(const uint4*)(hb + (size_t)c1 * DIM);
        uint4 u2 = *(const uint4*)(hb + (size_t)c2 * DIM);
        uint4 u3 = *(const uint4*)(hb + (size_t)c3 * DIM);
        ACC8(u0, aA0, aA1);
        ACC8(u1, aB0, aB1);
        ACC8(u2, aC0, aC1);
        ACC8(u3, aD0, aD1);
      }
      for (; i < cnt; ++i) {
        int c0 = cp[i];
        uint4 u0 = *(const uint4*)(hb + (size_t)c0 * DIM);
        ACC8(u0, aA0, aA1);
      }
      {
        uint4 us = *(const uint4*)(hb + (size_t)r * DIM);
        ACC8(us, aA0, aA1);
      }
      float s0x = (aA0.x + aB0.x) + (aC0.x + aD0.x);
      float s0y = (aA0.y + aB0.y) + (aC0.y + aD0.y);
      float s0z = (aA0.z + aB0.z) + (aC0.z + aD0.z);
      float s0w = (aA0.w + aB0.w) + (aC0.w + aD0.w);
      float s1x = (aA1.x + aB1.x) + (aC1.x + aD1.x);
      float s1y = (aA1.y + aB1.y) + (aC1.y + aD1.y);
      float s1z = (aA1.z + aB1.z) + (aC1.z + aD1.z);
      float s1w = (aA1.w + aB1.w) + (aC1.w + aD1.w);
      __half2 p0 = __floats2half2_rn(fmaxf(dr * s0x, 0.f), fmaxf(dr * s0y, 0.f));
      __half2 p1 = __floats2half2_rn(fmaxf(dr * s0z, 0.f), fmaxf(dr * s0w, 0.f));
      __half2 p2 = __floats2half2_rn(fmaxf(dr * s1x, 0.f), fmaxf(dr * s1y, 0.f));
      __half2 p3 = __floats2half2_rn(fmaxf(dr * s1z, 0.f), fmaxf(dr * s1w, 0.f));
      uint4 u;
      u.x = *(unsigned int*)&p0;
      u.y = *(unsigned int*)&p1;
      u.z = *(unsigned int*)&p2;
      u.w = *(unsigned int*)&p3;
      *(uint4*)&smA[rowin][q * 8] = u;
    } else {
      // zero-fill so MFMA reads defined data (unused rows)
      *(uint4*)&smA[rowin][q * 8] = make_uint4(0, 0, 0, 0);
    }
  }
  __syncthreads();
  // ---- phase 2: gemm on the 16-row tile; wave wv covers cols [wv*32, wv*32+32)
  {
    int l15 = lane & 15, lg = lane >> 4;
    int cb = wv * 32;
    f16x8 bfr[4][2];
#pragma unroll
    for (int ct = 0; ct < 2; ++ct) {
      int c = cb + ct * 16 + l15;
      const f16* wp = (const f16*)Wt + (size_t)c * DIM + lg * 8;
#pragma unroll
      for (int ks = 0; ks < 4; ++ks) bfr[ks][ct] = *(const f16x8*)(wp + ks * 32);
    }
    float bv[2];
#pragma unroll
    for (int ct = 0; ct < 2; ++ct) bv[ct] = bias[cb + ct * 16 + l15];
    f16x8 afr[4];
#pragma unroll
    for (int ks = 0; ks < 4; ++ks)
      afr[ks] = *(const f16x8*)&smA[l15][ks * 32 + lg * 8];
    f32x4 acc[2];
#pragma unroll
    for (int ct = 0; ct < 2; ++ct) acc[ct] = (f32x4){0.f, 0.f, 0.f, 0.f};
#pragma unroll
    for (int ks = 0; ks < 4; ++ks)
#pragma unroll
      for (int ct = 0; ct < 2; ++ct)
        acc[ct] = __builtin_amdgcn_mfma_f32_16x16x32_f16(afr[ks], bfr[ks][ct], acc[ct], 0, 0, 0);
#pragma unroll
    for (int j = 0; j < 4; ++j) {
      int r = blockIdx.x * 16 + lg * 4 + j;
      if (r < N) {
        float dr = dis[r];
#pragma unroll
        for (int ct = 0; ct < 2; ++ct) {
          float o = (acc[ct][j] + bv[ct]) * dr;
          Ho[(size_t)r * DIM + cb + ct * 16 + l15] = __float2half(o);
        }
      }
    }
  }
}

// ---------------- final aggregation (standalone) ----------------

__global__ __launch_bounds__(256) void k_agg(
    const __half* __restrict__ Hh, __half* __restrict__ Ah,
    const int* __restrict__ csrc, const int* __restrict__ cntA,
    const float* __restrict__ dis, int N) {
  int wave = (int)(((size_t)blockIdx.x * blockDim.x + threadIdx.x) >> 6);
  int lane = threadIdx.x & 63;
  int g = lane >> 4;
  int q = lane & 15;
  int r = wave * 4 + g;
  if (r >= N) return;
  int cnt = cntA[r];
  if (cnt > CPAD) cnt = CPAD;
  float dr = dis[r];
  const int* cp = csrc + ((size_t)r << 6);
  const f16* hb = (const f16*)Hh + q * 8;
  float4 aA0 = {0,0,0,0}, aA1 = {0,0,0,0};
  float4 aB0 = {0,0,0,0}, aB1 = {0,0,0,0};
  float4 aC0 = {0,0,0,0}, aC1 = {0,0,0,0};
  float4 aD0 = {0,0,0,0}, aD1 = {0,0,0,0};
  int i = 0;
  for (; i + 3 < cnt; i += 4) {
    int c0 = cp[i], c1 = cp[i + 1], c2 = cp[i + 2], c3 = cp[i + 3];
    uint4 u0 = *(const uint4*)(hb + (size_t)c0 * DIM);
    uint4 u1 = *(const uint4*)(hb + (size_t)c1 * DIM);
    uint4 u2 = *(const uint4*)(hb + (size_t)c2 * DIM);
    uint4 u3 = *(const uint4*)(hb + (size_t)c3 * DIM);
    ACC8(u0, aA0, aA1);
    ACC8(u1, aB0, aB1);
    ACC8(u2, aC0, aC1);
    ACC8(u3, aD0, aD1);
  }
  for (; i < cnt; ++i) {
    int c0 = cp[i];
    uint4 u0 = *(const uint4*)(hb + (size_t)c0 * DIM);
    ACC8(u0, aA0, aA1);
  }
  {
    uint4 us = *(const uint4*)(hb + (size_t)r * DIM);
    ACC8(us, aA0, aA1);
  }
  float s0x = (aA0.x + aB0.x) + (aC0.x + aD0.x);
  float s0y = (aA0.y + aB0.y) + (aC0.y + aD0.y);
  float s0z = (aA0.z + aB0.z) + (aC0.z + aD0.z);
  float s0w = (aA0.w + aB0.w) + (aC0.w + aD0.w);
  float s1x = (aA1.x + aB1.x) + (aC1.x + aD1.x);
  float s1y = (aA1.y + aB1.y) + (aC1.y + aD1.y);
  float s1z = (aA1.z + aB1.z) + (aC1.z + aD1.z);
  float s1w = (aA1.w + aB1.w) + (aC1.w + aD1.w);
  __half2 p0 = __floats2half2_rn(fmaxf(dr * s0x, 0.f), fmaxf(dr * s0y, 0.f));
  __half2 p1 = __floats2half2_rn(fmaxf(dr * s0z, 0.f), fmaxf(dr * s0w, 0.f));
  __half2 p2 = __floats2half2_rn(fmaxf(dr * s1x, 0.f), fmaxf(dr * s1y, 0.f));
  __half2 p3 = __floats2half2_rn(fmaxf(dr * s1z, 0.f), fmaxf(dr * s1w, 0.f));
  uint4 u;
  u.x = *(unsigned int*)&p0;
  u.y = *(unsigned int*)&p1;
  u.z = *(unsigned int*)&p2;
  u.w = *(unsigned int*)&p3;
  *(uint4*)((f16*)Ah + (size_t)r * DIM + q * 8) = u;
}
#undef ACC8

// ---------------- pooling + head ----------------

__device__ __forceinline__ int lower_bound_batch(const int* batch, int N, int g) {
  int lo = 0, hi = N;
  while (lo < hi) {
    int mid = (lo + hi) >> 1;
    if (batch[mid] < g) lo = mid + 1; else hi = mid;
  }
  return lo;
}

__global__ void k_pool1(const __half* __restrict__ A, const int* __restrict__ batch,
                        int N, float* __restrict__ part) {
  int g = blockIdx.x / PSLICE, sl = blockIdx.x % PSLICE;
  int c = threadIdx.x;
  int s = lower_bound_batch(batch, N, g);
  int e = lower_bound_batch(batch, N, g + 1);
  int len = e - s;
  int ns = s + (len * sl) / PSLICE;
  int ne = s + (len * (sl + 1)) / PSLICE;
  float sum = 0.f, mx = -INFINITY;
  for (int n = ns; n < ne; ++n) {
    float v = __half2float(A[(size_t)n * DIM + c]);
    sum += v;
    mx = fmaxf(mx, v);
  }
  part[((size_t)(g * PSLICE + sl) * 2 + 0) * DIM + c] = sum;
  part[((size_t)(g * PSLICE + sl) * 2 + 1) * DIM + c] = mx;
}

__global__ void k_head(const float* __restrict__ part, const int* __restrict__ batch,
                       int N, const float* __restrict__ Wm1,
                       const float* __restrict__ bm1, const float* __restrict__ Wm2,
                       const float* __restrict__ bm2, float* __restrict__ out) {
  __shared__ float gs[256];
  __shared__ float hs[DIM];
  int g = blockIdx.x;
  int c = threadIdx.x;
  float sum = 0.f, mx = -INFINITY;
  for (int sl = 0; sl < PSLICE; ++sl) {
    sum += part[((size_t)(g * PSLICE + sl) * 2 + 0) * DIM + c];
    mx = fmaxf(mx, part[((size_t)(g * PSLICE + sl) * 2 + 1) * DIM + c]);
  }
  int s = lower_bound_batch(batch, N, g);
  int e = lower_bound_batch(batch, N, g + 1);
  gs[c] = sum / ((float)(e - s) + 1e-12f);
  gs[c + 128] = mx;
  __syncthreads();
  float acc = bm1[c];
#pragma unroll 8
  for (int k = 0; k < 256; ++k) acc = fmaf(gs[k], Wm1[k * DIM + c], acc);
  hs[c] = fmaxf(acc, 0.f);
  __syncthreads();
  if (c < NCLS) {
    float a2 = bm2[c];
#pragma unroll 8
    for (int k = 0; k < DIM; ++k) a2 = fmaf(hs[k], Wm2[k * NCLS + c], a2);
    out[(size_t)g * NCLS + c] = a2;
  }
}

// ---------------- host ----------------

static inline size_t al256(size_t x) { return (x + 255) & ~(size_t)255; }

extern "C" void kernel_launch(void* const* d_in, const int* in_sizes, int n_in,
                              void* d_out, int out_size, void* d_ws, size_t ws_size,
                              hipStream_t stream) {
  const float* X = (const float*)d_in[0];
  const int* EI = (const int*)d_in[1];
  const int* batch = (const int*)d_in[2];
  const float* W1 = (const float*)d_in[4];
  const float* b1 = (const float*)d_in[5];
  const float* W2 = (const float*)d_in[6];
  const float* b2 = (const float*)d_in[7];
  const float* W3 = (const float*)d_in[8];
  const float* b3 = (const float*)d_in[9];
  const float* Wm1 = (const float*)d_in[10];
  const float* bm1 = (const float*)d_in[11];
  const float* Wm2 = (const float*)d_in[12];
  const float* bm2 = (const float*)d_in[13];
  float* OUT = (float*)d_out;

  const int N = in_sizes[0] / DIM;
  const int E = in_sizes[1] / 2;
  const int G = NG;

  const int* EI_row = EI;
  const int* EI_col = EI + E;

  char* p = (char*)d_ws;
  size_t off = 0;
  auto take = [&](size_t bytes) { void* r = p + off; off = al256(off + bytes); return r; };

  int* cnt = (int*)take((size_t)N * 4);
  int* bcnt = (int*)take((size_t)NOWN * NPBLK * 4);
  int* ovfn = (int*)take(256);
  unsigned long long* ovf = (unsigned long long*)take((size_t)OVCAP * 8);
  float* dis = (float*)take((size_t)N * 4);
  int* csrc = (int*)take((size_t)N * CPAD * 4);
  unsigned* buckets = (unsigned*)take((size_t)NOWN * NPBLK * OCAP * 4);
  __half* HA = (__half*)take((size_t)N * DIM * 2);
  __half* HB = (__half*)take((size_t)N * DIM * 2);
  __half* Ah = (__half*)take((size_t)N * DIM * 2);
  __half* Wt1 = (__half*)take((size_t)DIM * DIM * 2);
  __half* Wt2 = (__half*)take((size_t)DIM * DIM * 2);
  __half* Wt3 = (__half*)take((size_t)DIM * DIM * 2);
  float* part = (float*)take((size_t)G * PSLICE * 2 * DIM * 4);
  (void)ws_size; (void)n_in; (void)out_size;

  hipMemsetAsync(ovfn, 0, 4, stream);

  // preprocessing: partition (+ fused weight transpose), LDS-CSR assembly
  k_part<<<NPBLK + WTBLK, 256, 0, stream>>>(EI_row, EI_col, E, buckets, bcnt,
                                            ovf, ovfn, W1, W2, W3, Wt1, Wt2, Wt3);
  const int placeLds = ((RPB + 3) & ~3) * 4 + RPB * 64 * 4;  // ~100.5 KB
  k_place<<<NOWN, 256, placeLds, stream>>>(buckets, bcnt, ovf, ovfn, cnt, dis, csrc, N);

  const int tiles16 = (N + 15) / 16;
  const int aggBlocks = (N * 16 + 255) / 256;

  // layer 1 GEMM (fp32 X cast in-register)
  k_gemm<1><<<512, 256, 0, stream>>>(X, Wt1, b1, dis, HA, N);
  // agg1 + gemm2 fused
  k_agge<<<tiles16, 256, 0, stream>>>(HA, Wt2, b2, dis, HB, csrc, cnt, N);
  // agg2 + gemm3 fused
  k_agge<<<tiles16, 256, 0, stream>>>(HB, Wt3, b3, dis, HA, csrc, cnt, N);
  // agg3 (final)
  k_agg<<<aggBlocks, 256, 0, stream>>>(HA, Ah, csrc, cnt, dis, N);

  // pooling + head
  k_pool1<<<G * PSLICE, DIM, 0, stream>>>(Ah, batch, N, part);
  k_head<<<G, DIM, 0, stream>>>(part, batch, N, Wm1, bm1, Wm2, bm2, OUT);
}